// Round 1
// baseline (1172.462 us; speedup 1.0000x reference)
//
#include <hip/hip_runtime.h>

#define BN_EPS 1e-5f

__device__ __forceinline__ float4 ld4(const float* p){ return *reinterpret_cast<const float4*>(p); }
__device__ __forceinline__ void st4(float* p, float4 v){ *reinterpret_cast<float4*>(p) = v; }
__device__ __forceinline__ void fma4(float4& a, float s, float4 w){
  a.x = fmaf(s, w.x, a.x); a.y = fmaf(s, w.y, a.y);
  a.z = fmaf(s, w.z, a.z); a.w = fmaf(s, w.w, a.w);
}

// --- normalization + CSR build ---------------------------------------------

__global__ __launch_bounds__(256) void k_init(float* deg, int* cnt, int N){
  int i = blockIdx.x*256 + threadIdx.x;
  if (i < N){ deg[i] = 1.0f; cnt[i] = 0; }   // self-loop weight 1
}

__global__ __launch_bounds__(256) void k_edge_deg(const int* __restrict__ col, const float* __restrict__ ew,
                                                  float* deg, int* cnt, int E){
  int e = blockIdx.x*256 + threadIdx.x;
  if (e < E){ int c = col[e]; atomicAdd(&deg[c], ew[e]); atomicAdd(&cnt[c], 1); }
}

__global__ __launch_bounds__(256) void k_dis(float* deg, int N){
  int i = blockIdx.x*256 + threadIdx.x;
  if (i < N){ float d = deg[i]; deg[i] = d > 0.f ? rsqrtf(d) : 0.f; }  // in-place -> dis
}

// exclusive scan of cnt -> row_start (1024 elems per block)
__global__ __launch_bounds__(256) void k_scanA(const int* __restrict__ cnt, int* __restrict__ row_start,
                                               int* __restrict__ bsum, int N){
  __shared__ int sh[256];
  int t = threadIdx.x;
  int base = blockIdx.x*1024 + t*4;
  int v[4];
  #pragma unroll
  for (int j=0;j<4;++j){ int i = base+j; v[j] = (i<N) ? cnt[i] : 0; }
  int s = v[0]+v[1]+v[2]+v[3];
  sh[t] = s;
  __syncthreads();
  #pragma unroll
  for (int off=1; off<256; off<<=1){
    int x = (t>=off) ? sh[t-off] : 0;
    __syncthreads();
    sh[t] += x;
    __syncthreads();
  }
  int excl = sh[t] - s;
  #pragma unroll
  for (int j=0;j<4;++j){ int i = base+j; if (i<N) row_start[i] = excl; excl += v[j]; }
  if (t == 255) bsum[blockIdx.x] = sh[255];
}

__global__ void k_scanB(int* bsum, int nb){
  if (threadIdx.x == 0 && blockIdx.x == 0){
    int run = 0;
    for (int i=0;i<nb;++i){ int t = bsum[i]; bsum[i] = run; run += t; }
    bsum[nb] = run;
  }
}

__global__ __launch_bounds__(256) void k_scanC(int* __restrict__ row_start, int* __restrict__ cursor,
                                               const int* __restrict__ bsum, int N, int nb){
  int i = blockIdx.x*256 + threadIdx.x;
  if (i < N){
    int v = row_start[i] + bsum[i>>10];
    row_start[i] = v;
    cursor[i] = v;
  }
  if (i == 0) row_start[N] = bsum[nb];
}

__global__ __launch_bounds__(256) void k_scatter(const int* __restrict__ row, const int* __restrict__ col,
                                                 const float* __restrict__ ew, const float* __restrict__ dis,
                                                 int* cursor, int* __restrict__ csr_src,
                                                 float* __restrict__ csr_wn, int E){
  int e = blockIdx.x*256 + threadIdx.x;
  if (e < E){
    int r = row[e], c = col[e];
    int pos = atomicAdd(&cursor[c], 1);
    csr_src[pos] = r;
    csr_wn[pos] = ew[e]*dis[r]*dis[c];
  }
}

// --- C[N,128] = A[N,128] @ W[128,128], fp32, W in LDS -----------------------

__global__ __launch_bounds__(256) void k_gemm128(const float* __restrict__ A, const float* __restrict__ W,
                                                 float* __restrict__ C, int N){
  __shared__ float Wl[128*128];   // 64 KB
  int t = threadIdx.x;
  #pragma unroll
  for (int i=0;i<16;++i)
    reinterpret_cast<float4*>(Wl)[t + 256*i] = reinterpret_cast<const float4*>(W)[t + 256*i];
  __syncthreads();
  int tx = t & 31, ty = t >> 5;           // tx -> 4 cols, ty -> 4 rows
  int rowBase = blockIdx.x*32 + ty*4;
  const float* a[4]; bool val[4];
  #pragma unroll
  for (int j=0;j<4;++j){ int r = rowBase+j; val[j] = r < N; a[j] = A + (size_t)(val[j]?r:0)*128; }
  float4 acc[4];
  #pragma unroll
  for (int j=0;j<4;++j) acc[j] = make_float4(0.f,0.f,0.f,0.f);
  const float* wc = Wl + tx*4;
  #pragma unroll 4
  for (int k=0;k<128;k+=4){
    float4 w0 = ld4(wc + (size_t)(k+0)*128);
    float4 w1 = ld4(wc + (size_t)(k+1)*128);
    float4 w2 = ld4(wc + (size_t)(k+2)*128);
    float4 w3 = ld4(wc + (size_t)(k+3)*128);
    #pragma unroll
    for (int j=0;j<4;++j){
      float4 xv = ld4(a[j] + k);
      fma4(acc[j], xv.x, w0);
      fma4(acc[j], xv.y, w1);
      fma4(acc[j], xv.z, w2);
      fma4(acc[j], xv.w, w3);
    }
  }
  #pragma unroll
  for (int j=0;j<4;++j)
    if (val[j]) st4(C + (size_t)(rowBase+j)*128 + tx*4, acc[j]);
}

// --- CSR aggregation: 32 lanes per node, float4 over 128 feats --------------

__global__ __launch_bounds__(256) void k_agg(const float* __restrict__ h, const int* __restrict__ row_start,
                                             const int* __restrict__ csr_src, const float* __restrict__ csr_wn,
                                             const float* __restrict__ dis, const float* __restrict__ bias,
                                             float* __restrict__ out, int N){
  int g = (blockIdx.x*256 + threadIdx.x) >> 5;   // node
  int lane = threadIdx.x & 31;
  if (g >= N) return;
  int s = row_start[g], e = row_start[g+1];
  float ds = dis[g];
  float4 acc = make_float4(0.f,0.f,0.f,0.f);
  fma4(acc, ds*ds, ld4(h + (size_t)g*128 + lane*4));        // self loop
  for (int i=s;i<e;++i){
    int src = csr_src[i];
    float w = csr_wn[i];
    fma4(acc, w, ld4(h + (size_t)src*128 + lane*4));
  }
  float4 b = ld4(bias + lane*4);
  acc.x += b.x; acc.y += b.y; acc.z += b.z; acc.w += b.w;
  st4(out + (size_t)g*128 + lane*4, acc);
}

// --- BatchNorm (batch stats, biased var) + ReLU ------------------------------

__global__ void k_zero256(float* p){ p[threadIdx.x] = 0.f; }

__global__ __launch_bounds__(256) void k_bn_stats(const float* __restrict__ x, float* __restrict__ stats, int N){
  __shared__ float lsum[128], lsq[128];
  int t = threadIdx.x;
  int f = t & 127, half = t >> 7;
  float s = 0.f, q = 0.f;
  int r0 = blockIdx.x*256 + half;
  #pragma unroll 4
  for (int i=0;i<128;++i){
    int rr = r0 + i*2;
    if (rr < N){ float v = x[(size_t)rr*128 + f]; s += v; q = fmaf(v, v, q); }
  }
  if (half == 0){ lsum[f] = s; lsq[f] = q; }
  __syncthreads();
  if (half == 1){ lsum[f] += s; lsq[f] += q; }
  __syncthreads();
  if (half == 1){
    atomicAdd(&stats[f], lsum[f]);
    atomicAdd(&stats[128+f], lsq[f]);
  }
}

__global__ void k_bn_fin(const float* __restrict__ stats, const float* __restrict__ g,
                         const float* __restrict__ be, float* __restrict__ ab, int N){
  int f = threadIdx.x;
  if (f < 128){
    float invN = 1.0f / (float)N;
    float mean = stats[f]*invN;
    float var = stats[128+f]*invN - mean*mean;
    var = var > 0.f ? var : 0.f;
    float inv = rsqrtf(var + BN_EPS);
    float a = g[f]*inv;
    ab[f] = a;
    ab[128+f] = be[f] - mean*a;
  }
}

__global__ __launch_bounds__(256) void k_bn_apply(float* __restrict__ x, const float* __restrict__ ab, int total4){
  int i = blockIdx.x*256 + threadIdx.x;
  if (i >= total4) return;
  int f = (i & 31)*4;
  float4 v = ld4(x + (size_t)i*4);
  float4 a = ld4(ab + f);
  float4 c = ld4(ab + 128 + f);
  v.x = fmaxf(fmaf(v.x, a.x, c.x), 0.f);
  v.y = fmaxf(fmaf(v.y, a.y, c.y), 0.f);
  v.z = fmaxf(fmaf(v.z, a.z, c.z), 0.f);
  v.w = fmaxf(fmaf(v.w, a.w, c.w), 0.f);
  st4(x + (size_t)i*4, v);
}

// --- out (+)= o @ Wlin_layer (+ blin on first layer) -------------------------

__global__ __launch_bounds__(256) void k_lin(const float* __restrict__ o, const float* __restrict__ Wl_g,
                                             const float* __restrict__ blin, float* __restrict__ out,
                                             int N, int initFlag){
  __shared__ float Wl[1280];
  int t = threadIdx.x;
  for (int i=t;i<1280;i+=256) Wl[i] = Wl_g[i];
  __syncthreads();
  int row = blockIdx.x*256 + t;
  if (row >= N) return;
  float acc[10];
  #pragma unroll
  for (int c=0;c<10;++c) acc[c] = initFlag ? blin[c] : out[(size_t)row*10 + c];
  const float* orow = o + (size_t)row*128;
  #pragma unroll 4
  for (int k=0;k<128;k+=4){
    float4 v = ld4(orow + k);
    #pragma unroll
    for (int c=0;c<10;++c){
      acc[c] = fmaf(v.x, Wl[(k+0)*10+c], acc[c]);
      acc[c] = fmaf(v.y, Wl[(k+1)*10+c], acc[c]);
      acc[c] = fmaf(v.z, Wl[(k+2)*10+c], acc[c]);
      acc[c] = fmaf(v.w, Wl[(k+3)*10+c], acc[c]);
    }
  }
  #pragma unroll
  for (int c=0;c<10;++c) out[(size_t)row*10 + c] = acc[c];
}

// -----------------------------------------------------------------------------

extern "C" void kernel_launch(void* const* d_in, const int* in_sizes, int n_in,
                              void* d_out, int out_size, void* d_ws, size_t ws_size,
                              hipStream_t stream){
  const float* x    = (const float*)d_in[0];
  const int*   ei   = (const int*)d_in[1];
  const float* ew   = (const float*)d_in[2];
  const float* W[3]  = {(const float*)d_in[3], (const float*)d_in[7],  (const float*)d_in[11]};
  const float* b[3]  = {(const float*)d_in[4], (const float*)d_in[8],  (const float*)d_in[12]};
  const float* g[3]  = {(const float*)d_in[5], (const float*)d_in[9],  (const float*)d_in[13]};
  const float* be[3] = {(const float*)d_in[6], (const float*)d_in[10], (const float*)d_in[14]};
  const float* Wlin = (const float*)d_in[15];
  const float* blin = (const float*)d_in[16];
  float* out = (float*)d_out;

  int N = in_sizes[0] / 128;
  int E = in_sizes[2];
  const int* row = ei;        // sources
  const int* col = ei + E;    // targets

  // workspace carve (~117 MB total)
  char* p = (char*)d_ws;
  auto carve = [&](size_t bytes) -> void* {
    void* q = (void*)p;
    p += (bytes + 255) & ~(size_t)255;
    return q;
  };
  int nb = (N + 1023) / 1024;
  float* deg     = (float*)carve((size_t)N*4);        // becomes dis after k_dis
  int*   cnt     = (int*)  carve((size_t)N*4);
  int*   rstart  = (int*)  carve((size_t)(N+1)*4);
  int*   cursor  = (int*)  carve((size_t)N*4);
  int*   bsum    = (int*)  carve((size_t)(nb+1)*4);
  int*   csr_src = (int*)  carve((size_t)E*4);
  float* csr_wn  = (float*)carve((size_t)E*4);
  float* stats   = (float*)carve(256*4);
  float* ab      = (float*)carve(256*4);
  float* h       = (float*)carve((size_t)N*128*4);
  float* o       = (float*)carve((size_t)N*128*4);

  int gN = (N+255)/256, gE = (E+255)/256;
  k_init    <<<gN,256,0,stream>>>(deg, cnt, N);
  k_edge_deg<<<gE,256,0,stream>>>(col, ew, deg, cnt, E);
  k_dis     <<<gN,256,0,stream>>>(deg, N);
  k_scanA   <<<nb,256,0,stream>>>(cnt, rstart, bsum, N);
  k_scanB   <<<1,64,0,stream>>>(bsum, nb);
  k_scanC   <<<gN,256,0,stream>>>(rstart, cursor, bsum, N, nb);
  k_scatter <<<gE,256,0,stream>>>(row, col, ew, deg, cursor, csr_src, csr_wn, E);

  const float* xin = x;
  for (int l=0;l<3;++l){
    k_gemm128 <<<(N+31)/32,256,0,stream>>>(xin, W[l], h, N);
    k_zero256 <<<1,256,0,stream>>>(stats);
    k_agg     <<<(N*32+255)/256,256,0,stream>>>(h, rstart, csr_src, csr_wn, deg, b[l], o, N);
    k_bn_stats<<<gN,256,0,stream>>>(o, stats, N);
    k_bn_fin  <<<1,128,0,stream>>>(stats, g[l], be[l], ab, N);
    k_bn_apply<<<(N*32+255)/256,256,0,stream>>>(o, ab, N*32);
    k_lin     <<<gN,256,0,stream>>>(o, Wlin + (size_t)l*128*10, blin, out, N, l==0 ? 1 : 0);
    xin = o;
  }
}